// Round 12
// baseline (313.228 us; speedup 1.0000x reference)
//
#include <hip/hip_runtime.h>
#include <hip/hip_bf16.h>
#include <stdint.h>

typedef unsigned short u16;
typedef uint32_t u32;
typedef __bf16 bf16x8 __attribute__((ext_vector_type(8)));
typedef __bf16 bf16x2v __attribute__((ext_vector_type(2)));
typedef float f32x2 __attribute__((ext_vector_type(2)));
typedef float f32x4 __attribute__((ext_vector_type(4)));
typedef float f32x16 __attribute__((ext_vector_type(16)));
typedef u16 u16x4v __attribute__((ext_vector_type(4)));
typedef u32 u32x2 __attribute__((ext_vector_type(2)));

#define AS1 __attribute__((address_space(1)))
#define AS3 __attribute__((address_space(3)))

__device__ __forceinline__ void gld_lds16(const u16* g, u16* l) {
    __builtin_amdgcn_global_load_lds((const AS1 uint32_t*)g, (AS3 uint32_t*)l, 16, 0, 0);
}

__device__ __forceinline__ u16 f2bf(float f) {
    union { float f; uint32_t u; } v; v.f = f;
    uint32_t u = v.u;
    return (u16)((u + 0x7FFFu + ((u >> 16) & 1u)) >> 16);
}

// P pack: hardware v_cvt_pk_bf16_f32 via vector fptrunc (RTNE). R4->R5 measured
// -8pts VALUBusy vs the ROCm header __float22bfloat162_rn bit-twiddle path.
__device__ __forceinline__ u32 pkbf16(float lo, float hi) {
    f32x2 e; e[0] = lo; e[1] = hi;
    union { bf16x2v b; u32 d; } u;
    u.b = __builtin_convertvector(e, bf16x2v);
    return u.d;
}

__device__ __forceinline__ u32x2 pl32swap(u32 a, u32 b) {
#if __has_builtin(__builtin_amdgcn_permlane32_swap)
    return __builtin_amdgcn_permlane32_swap(a, b, false, false);
#else
    asm volatile("v_permlane32_swap_b32 %0, %1" : "+v"(a), "+v"(b));
    u32x2 r; r[0] = a; r[1] = b; return r;
#endif
}

// softmax+pack for one sacc: p=exp2(s), l partial on VALU, C-frag -> B-frag via
// cvt_pk + permlane32_swap. Identical math since R5 (absmax stable at 2^-11).
__device__ __forceinline__ void smpack(const f32x16& sv, f32x2& la,
                                       bf16x8& A0v, bf16x8& A1v) {
    u32 pk[8];
#pragma unroll
    for (int p = 0; p < 8; ++p) {
        const float e0 = __builtin_amdgcn_exp2f(sv[2 * p]);
        const float e1 = __builtin_amdgcn_exp2f(sv[2 * p + 1]);
        f32x2 e2; e2[0] = e0; e2[1] = e1;
        la += e2;
        pk[p] = pkbf16(e0, e1);
    }
    const u32x2 r02 = pl32swap(pk[0], pk[2]);
    const u32x2 r13 = pl32swap(pk[1], pk[3]);
    const u32x2 r46 = pl32swap(pk[4], pk[6]);
    const u32x2 r57 = pl32swap(pk[5], pk[7]);
    union { u32 d[4]; bf16x8 v; } A0, A1;
    A0.d[0] = r02[0]; A0.d[1] = r13[0]; A0.d[2] = r02[1]; A0.d[3] = r13[1];
    A1.d[0] = r46[0]; A1.d[1] = r57[0]; A1.d[2] = r46[1]; A1.d[3] = r57[1];
    A0v = A0.v; A1v = A1.v;
}

// exp2 scale folded into Q at gemm1 epilogue: 0.125 * log2(e)
#define QSCALE 0.18033688011112042f

// ---------------- cast fp32 -> bf16 (vectorized) ----------------
__global__ void cast_f32_bf16(const float* __restrict__ in, u16* __restrict__ out, int n4) {
    int i = blockIdx.x * blockDim.x + threadIdx.x;
    if (i < n4) {
        float4 f = ((const float4*)in)[i];
        u16x4v o;
        o.x = f2bf(f.x); o.y = f2bf(f.y); o.z = f2bf(f.z); o.w = f2bf(f.w);
        ((u16x4v*)out)[i] = o;
    }
}

// ---------------- bt-GEMM: C[m,n] = sum_k A[m,k]*B[n,k] + bias[n] ----------------
// MODE 0: fp32 out, row-major ldc.
// MODE 1: qkv split epilogue -> qb (bf16, prescaled), kb (bf16), vT (bf16, [h][hd][8192]).
// T1: bijective XCD swizzle on flat block id (nwg%8==0 for both launches).
// R10 (kept): BK=64 halves barriers (total 265.5->262.9); (256,3) from R9; staging
// uses the 8-chunk rotate pattern. R8's dbuf was negative; m131-m141 say this 2-phase
// structure is now within its ceiling band -- no further schedule surgery here.
template <int MODE>
__global__ __launch_bounds__(256, 3) void gemm_bt(
    const u16* __restrict__ A, const u16* __restrict__ B,
    const float* __restrict__ bias, float* __restrict__ Cf,
    u16* __restrict__ qb, u16* __restrict__ kb, u16* __restrict__ vT,
    int K, int ldc)
{
    __shared__ __align__(16) u16 As[128 * 64];
    __shared__ __align__(16) u16 Bs[128 * 64];
    const int tid = threadIdx.x;
    const int lane = tid & 63;
    const int w = tid >> 6;
    const int wm = (w >> 1) << 6;
    const int wn = (w & 1) << 6;
    const int r = lane & 15;
    const int q = lane >> 4;

    // XCD-aware bijective block swizzle (each XCD gets a contiguous panel chunk)
    const int nwgx = gridDim.x;
    const int flat = blockIdx.y * nwgx + blockIdx.x;
    const int cpx = (nwgx * gridDim.y) >> 3;
    const int swz = (flat & 7) * cpx + (flat >> 3);
    const int m0 = (swz / nwgx) << 7;
    const int n0 = (swz % nwgx) << 7;

    const f32x4 zero4 = {0.f, 0.f, 0.f, 0.f};
    f32x4 acc[4][4];
#pragma unroll
    for (int i = 0; i < 4; ++i)
#pragma unroll
        for (int j = 0; j < 4; ++j) acc[i][j] = zero4;

    const int nk = K >> 6;   // 64-wide K-steps
    for (int kt = 0; kt < nk; ++kt) {
        const int kk = kt << 6;
        // stage 128 rows x 64 cols per matrix: 8 chunks/row, rotate phys = (cg+row)&7
#pragma unroll
        for (int p = 0; p < 4; ++p) {
            const int idx = (p << 8) + tid;
            const int row = idx >> 3;
            const int cg = ((idx & 7) - row) & 7;
            gld_lds16(A + (m0 + row) * K + kk + (cg << 3), &As[idx << 3]);
            gld_lds16(B + (n0 + row) * K + kk + (cg << 3), &Bs[idx << 3]);
        }
        __syncthreads();
#pragma unroll
        for (int s = 0; s < 2; ++s) {
            bf16x8 af[4], bf[4];
#pragma unroll
            for (int i = 0; i < 4; ++i) {
                const int ra = wm + (i << 4) + r;
                af[i] = *(const bf16x8*)&As[(ra << 6) + ((((s << 2) + q + ra) & 7) << 3)];
                const int rb = wn + (i << 4) + r;
                bf[i] = *(const bf16x8*)&Bs[(rb << 6) + ((((s << 2) + q + rb) & 7) << 3)];
            }
#pragma unroll
            for (int i = 0; i < 4; ++i)
#pragma unroll
                for (int j = 0; j < 4; ++j)
                    acc[i][j] = __builtin_amdgcn_mfma_f32_16x16x32_bf16(af[i], bf[j], acc[i][j], 0, 0, 0);
        }
        __syncthreads();
    }

#pragma unroll
    for (int j = 0; j < 4; ++j) {
        const int col = n0 + wn + (j << 4) + r;
        const float bv = bias[col];
        if (MODE == 0) {
#pragma unroll
            for (int i = 0; i < 4; ++i)
#pragma unroll
                for (int ii = 0; ii < 4; ++ii) {
                    const int rowg = m0 + wm + (i << 4) + (q << 2) + ii;
                    Cf[rowg * ldc + col] = acc[i][j][ii] + bv;
                }
        } else {
            // wave-uniform region decode per j-group (16 cols never straddle 64/192 boundaries)
            const int c0 = n0 + wn + (j << 4);
            const int h = c0 / 192;
            const int rem = c0 - h * 192;
            const int region = rem >> 6;
            const int colp = (h << 6) + (rem - (region << 6)) + r;
            if (region == 0) {
#pragma unroll
                for (int i = 0; i < 4; ++i)
#pragma unroll
                    for (int ii = 0; ii < 4; ++ii) {
                        const int rowg = m0 + wm + (i << 4) + (q << 2) + ii;
                        qb[rowg * 1024 + colp] = f2bf((acc[i][j][ii] + bv) * QSCALE);
                    }
            } else if (region == 1) {
#pragma unroll
                for (int i = 0; i < 4; ++i)
#pragma unroll
                    for (int ii = 0; ii < 4; ++ii) {
                        const int rowg = m0 + wm + (i << 4) + (q << 2) + ii;
                        kb[rowg * 1024 + colp] = f2bf(acc[i][j][ii] + bv);
                    }
            } else {
                // V transposed: vT[colp][rowg], rowg contiguous -> packed 8B stores
#pragma unroll
                for (int i = 0; i < 4; ++i) {
                    const int rowg0 = m0 + wm + (i << 4) + (q << 2);
                    u16x4v vv;
                    vv.x = f2bf(acc[i][j][0] + bv);
                    vv.y = f2bf(acc[i][j][1] + bv);
                    vv.z = f2bf(acc[i][j][2] + bv);
                    vv.w = f2bf(acc[i][j][3] + bv);
                    *(u16x4v*)&vT[(size_t)colp * 8192 + rowg0] = vv;
                }
            }
        }
    }
}

// ---------------- flash attention, direct-from-cache K/V (no LDS staging) ----------------
// R12: K/V frag reads go DIRECTLY to global (L1/L2-resident) -- the entire LDS staging
// apparatus (global_load_lds, double-buffer, per-kt __syncthreads) is deleted; the kt
// loop has ZERO barriers. Rationale: per-(b,h) K/V = 512 KB, 8 pairs/XCD = 4 MB =
// exactly one XCD L2 (FETCH 24.6 MB << 42 MB logical confirms residency); per-kt
// K-tile and V-tile are 8 KB each -> L1-resident, every line fully consumed across
// dc/mt frags. Catalog m168->m169 precedent: staging cache-fit data is pure overhead
// (+26% when dropped). Waves now free-run; 4 waves/SIMD desync naturally -> m114
// MFMA||VALU cross-wave overlap without source choreography (R7 showed forcing it
// in-wave hurts). Six structural variations left a ~24% no-pipe-busy stall; the
// barrier+LDS round-trip is the remaining suspect.
// Frag addresses: kt-invariant per-lane base + compile-time offsets.
//   K (mt,dc):  kb + (rowbase + kt*64 + mt*32 + c)*1024 + head*64 + dc*16 + h2*8
//   V (ht,mt,c16): vT + (head*64 + ht*32 + c)*8192 + rowbase + kt*64 + mt*32 + c16*16 + h2*8
// Q staging in LDS unchanged (init only). Bank conflicts should go to ~0.
// __launch_bounds__(256,2): grid 512 = 2 blocks/CU (grid-limited anyway).
__global__ __launch_bounds__(256, 2) void attn(
    const u16* __restrict__ qb, const u16* __restrict__ kb,
    const u16* __restrict__ vT, u16* __restrict__ vals)
{
    __shared__ __align__(16) u16 S[16384];   // Q staging only (256 rows x 64)

    const int tid  = threadIdx.x;
    const int lane = tid & 63;
    const int w    = tid >> 6;
    const int c    = lane & 31;   // row index of 32x32 A-frags / col of C-frags
    const int h2   = lane >> 5;   // lane half
    const int head = blockIdx.x;
    const int q0   = blockIdx.y << 8;   // 256 q-rows per block
    const int b    = blockIdx.z;
    const size_t rowbase = (size_t)b * 2048;

    // ---- stage Q (256 rows x 8 chunks of 8 u16), rotate swizzle ----
#pragma unroll
    for (int p = 0; p < 8; ++p) {
        const int idx = (p << 8) + tid;
        const int row = idx >> 3;
        const int cg  = ((idx & 7) - row) & 7;
        gld_lds16(qb + (rowbase + q0 + row) * 1024 + (head << 6) + (cg << 3), &S[idx << 3]);
    }
    __syncthreads();

    // ---- Q B-frags (loop-invariant): bq[dc][nt], lane holds Q[qr][16dc+8*h2+j] ----
    bf16x8 bq[4][2];
#pragma unroll
    for (int nt = 0; nt < 2; ++nt) {
        const int qr = (w << 6) + (nt << 5) + c;
#pragma unroll
        for (int dc = 0; dc < 4; ++dc)
            bq[dc][nt] = *(const bf16x8*)&S[(qr << 6) + ((((dc << 1) + h2 + qr) & 7) << 3)];
    }
    // no further writes to S -> no barrier needed; kt loop is barrier-free.

    // ---- direct K/V fragment pointers (per-lane, kt-invariant bases) ----
    const u16* kp = kb + (rowbase + c) * 1024 + (head << 6) + (h2 << 3);
    const u16* vp = vT + (size_t)((head << 6) + c) * 8192 + rowbase + (h2 << 3);

    f32x16 oacc[2][2];            // oacc[ht][nt]
    f32x2 la2[2];                 // l partial sums (lane-local column sums)
    f32x16 zero16;
#pragma unroll
    for (int i = 0; i < 16; ++i) {
        zero16[i] = 0.f;
        oacc[0][0][i] = 0.f; oacc[0][1][i] = 0.f;
        oacc[1][0][i] = 0.f; oacc[1][1][i] = 0.f;
    }
    la2[0][0] = 0.f; la2[0][1] = 0.f;
    la2[1][0] = 0.f; la2[1][1] = 0.f;

    for (int kt = 0; kt < 32; ++kt) {
#pragma unroll
        for (int mt = 0; mt < 2; ++mt) {
            // ---- K frags direct (4 x b128, L1-resident after first touch) ----
            const u16* kpm = kp + (mt << 15);   // + mt*32 rows * 1024
            bf16x8 ak[4];
#pragma unroll
            for (int dc = 0; dc < 4; ++dc)
                ak[dc] = *(const bf16x8*)&kpm[dc << 4];

            // ---- S^T = K Q^T ; dc=0 peeled with zero16 C-operand ----
            __builtin_amdgcn_s_setprio(1);
            f32x16 s0 = __builtin_amdgcn_mfma_f32_32x32x16_bf16(ak[0], bq[0][0], zero16, 0, 0, 0);
            f32x16 s1 = __builtin_amdgcn_mfma_f32_32x32x16_bf16(ak[0], bq[0][1], zero16, 0, 0, 0);
#pragma unroll
            for (int dc = 1; dc < 4; ++dc) {
                s0 = __builtin_amdgcn_mfma_f32_32x32x16_bf16(ak[dc], bq[dc][0], s0, 0, 0, 0);
                s1 = __builtin_amdgcn_mfma_f32_32x32x16_bf16(ak[dc], bq[dc][1], s1, 0, 0, 0);
            }
            __builtin_amdgcn_s_setprio(0);

            // ---- V^T A-frags direct (4 x b128) ----
            bf16x8 av[4];   // [ht*2 + c16]
#pragma unroll
            for (int ht = 0; ht < 2; ++ht)
#pragma unroll
                for (int c16 = 0; c16 < 2; ++c16)
                    av[(ht << 1) | c16] =
                        *(const bf16x8*)&vp[((size_t)ht << 18) + (mt << 5) + (c16 << 4)];

#pragma unroll
            for (int nt = 0; nt < 2; ++nt) {
                const f32x16& sv = (nt == 0) ? s0 : s1;   // compile-time select
                bf16x8 A0v, A1v;
                smpack(sv, la2[nt], A0v, A1v);

                __builtin_amdgcn_s_setprio(1);
                // O^T += V^T P^T
#pragma unroll
                for (int ht = 0; ht < 2; ++ht) {
                    oacc[ht][nt] = __builtin_amdgcn_mfma_f32_32x32x16_bf16(av[(ht << 1) | 0], A0v, oacc[ht][nt], 0, 0, 0);
                    oacc[ht][nt] = __builtin_amdgcn_mfma_f32_32x32x16_bf16(av[(ht << 1) | 1], A1v, oacc[ht][nt], 0, 0, 0);
                }
                __builtin_amdgcn_s_setprio(0);
            }
        }
        kp += 65536;   // +64 rows * 1024
        vp += 64;      // +64 kv
    }

    // ---- epilogue: l = own-half partial + other-half partial (shfl_xor 32) ----
#pragma unroll
    for (int nt = 0; nt < 2; ++nt) {
        float myl = la2[nt][0] + la2[nt][1];
        myl += __shfl_xor(myl, 32, 64);
        const float inv = 1.f / myl;
        const size_t orow = rowbase + q0 + (w << 6) + (nt << 5) + c;
#pragma unroll
        for (int ht = 0; ht < 2; ++ht)
#pragma unroll
            for (int r4 = 0; r4 < 4; ++r4) {
                u16x4v vv;
                vv.x = f2bf(oacc[ht][nt][4 * r4 + 0] * inv);
                vv.y = f2bf(oacc[ht][nt][4 * r4 + 1] * inv);
                vv.z = f2bf(oacc[ht][nt][4 * r4 + 2] * inv);
                vv.w = f2bf(oacc[ht][nt][4 * r4 + 3] * inv);
                const int hd0 = (ht << 5) + (r4 << 3) + (h2 << 2);
                *(u16x4v*)&vals[orow * 1024 + (head << 6) + hd0] = vv;
            }
    }
}

// ---------------- launcher ----------------
extern "C" void kernel_launch(void* const* d_in, const int* in_sizes, int n_in,
                              void* d_out, int out_size, void* d_ws, size_t ws_size,
                              hipStream_t stream) {
    (void)in_sizes; (void)n_in; (void)out_size; (void)ws_size;
    const float* x     = (const float*)d_in[0];   // [4,2048,1024]
    const float* w_qkv = (const float*)d_in[1];   // [3072,1024]
    const float* b_qkv = (const float*)d_in[2];   // [3072]
    const float* w_o   = (const float*)d_in[3];   // [1024,1024]
    const float* b_o   = (const float*)d_in[4];   // [1024]
    float* out = (float*)d_out;                   // [4,2048,1024]

    char* ws = (char*)d_ws;
    u16* xb    = (u16*)(ws);                          // 16 MB  [8192,1024]
    u16* wqkvb = (u16*)(ws + (size_t)(16 << 20));     //  6 MB  [3072,1024]
    u16* wob   = (u16*)(ws + (size_t)(22 << 20));     //  2 MB  [1024,1024]
    u16* qb    = (u16*)(ws + (size_t)(24 << 20));     // 16 MB  [8192,1024]
    u16* kb    = (u16*)(ws + (size_t)(40 << 20));     // 16 MB  [8192,1024]
    u16* vTb   = (u16*)(ws + (size_t)(56 << 20));     // 16 MB  [16,64,8192]
    u16* valsb = (u16*)(ws + (size_t)(72 << 20));     // 16 MB  [8192,1024]

    cast_f32_bf16<<<8192, 256, 0, stream>>>(x, xb, 2097152);
    cast_f32_bf16<<<3072, 256, 0, stream>>>(w_qkv, wqkvb, 786432);
    cast_f32_bf16<<<1024, 256, 0, stream>>>(w_o, wob, 262144);

    // qkv = x @ w_qkv^T + b_qkv -> split qb (prescaled) / kb / vT
    gemm_bt<1><<<dim3(24, 64), 256, 0, stream>>>(xb, wqkvb, b_qkv, nullptr,
                                                 qb, kb, vTb, 1024, 3072);

    // attention -> vals (bf16); 512 blocks = exactly 2/CU, (b,h) XCD-local
    attn<<<dim3(16, 8, 4), 256, 0, stream>>>(qb, kb, vTb, valsb);

    // out = vals @ w_o^T + b_o  (fp32 out)
    gemm_bt<0><<<dim3(8, 64), 256, 0, stream>>>(valsb, wob, b_o, out,
                                                nullptr, nullptr, nullptr, 1024, 1024);
}

// Round 13
// 241.138 us; speedup vs baseline: 1.2990x; 1.2990x over previous
//
#include <hip/hip_runtime.h>
#include <hip/hip_bf16.h>
#include <stdint.h>

typedef unsigned short u16;
typedef uint32_t u32;
typedef __bf16 bf16x8 __attribute__((ext_vector_type(8)));
typedef __bf16 bf16x2v __attribute__((ext_vector_type(2)));
typedef float f32x2 __attribute__((ext_vector_type(2)));
typedef float f32x4 __attribute__((ext_vector_type(4)));
typedef float f32x16 __attribute__((ext_vector_type(16)));
typedef u16 u16x4v __attribute__((ext_vector_type(4)));
typedef u32 u32x2 __attribute__((ext_vector_type(2)));

#define AS1 __attribute__((address_space(1)))
#define AS3 __attribute__((address_space(3)))

__device__ __forceinline__ void gld_lds16(const u16* g, u16* l) {
    __builtin_amdgcn_global_load_lds((const AS1 uint32_t*)g, (AS3 uint32_t*)l, 16, 0, 0);
}

__device__ __forceinline__ u16 f2bf(float f) {
    union { float f; uint32_t u; } v; v.f = f;
    uint32_t u = v.u;
    return (u16)((u + 0x7FFFu + ((u >> 16) & 1u)) >> 16);
}

// P pack: hardware v_cvt_pk_bf16_f32 via vector fptrunc (RTNE). R4->R5 measured
// -8pts VALUBusy vs the ROCm header __float22bfloat162_rn bit-twiddle path.
__device__ __forceinline__ u32 pkbf16(float lo, float hi) {
    f32x2 e; e[0] = lo; e[1] = hi;
    union { bf16x2v b; u32 d; } u;
    u.b = __builtin_convertvector(e, bf16x2v);
    return u.d;
}

__device__ __forceinline__ u32x2 pl32swap(u32 a, u32 b) {
#if __has_builtin(__builtin_amdgcn_permlane32_swap)
    return __builtin_amdgcn_permlane32_swap(a, b, false, false);
#else
    asm volatile("v_permlane32_swap_b32 %0, %1" : "+v"(a), "+v"(b));
    u32x2 r; r[0] = a; r[1] = b; return r;
#endif
}

// softmax+pack for one sacc: p=exp2(s), l partial on VALU, C-frag -> B-frag via
// cvt_pk + permlane32_swap. Identical math since R5 (absmax stable at 2^-11).
__device__ __forceinline__ void smpack(const f32x16& sv, f32x2& la,
                                       bf16x8& A0v, bf16x8& A1v) {
    u32 pk[8];
#pragma unroll
    for (int p = 0; p < 8; ++p) {
        const float e0 = __builtin_amdgcn_exp2f(sv[2 * p]);
        const float e1 = __builtin_amdgcn_exp2f(sv[2 * p + 1]);
        f32x2 e2; e2[0] = e0; e2[1] = e1;
        la += e2;
        pk[p] = pkbf16(e0, e1);
    }
    const u32x2 r02 = pl32swap(pk[0], pk[2]);
    const u32x2 r13 = pl32swap(pk[1], pk[3]);
    const u32x2 r46 = pl32swap(pk[4], pk[6]);
    const u32x2 r57 = pl32swap(pk[5], pk[7]);
    union { u32 d[4]; bf16x8 v; } A0, A1;
    A0.d[0] = r02[0]; A0.d[1] = r13[0]; A0.d[2] = r02[1]; A0.d[3] = r13[1];
    A1.d[0] = r46[0]; A1.d[1] = r57[0]; A1.d[2] = r46[1]; A1.d[3] = r57[1];
    A0v = A0.v; A1v = A1.v;
}

// exp2 scale folded into Q at gemm1 epilogue: 0.125 * log2(e)
#define QSCALE 0.18033688011112042f

// ---------------- fused cast fp32 -> bf16 for all three inputs ----------------
// R13: one launch instead of three (saves ~2 launch overheads). Region split is
// block-uniform except at the two boundaries (block 8192 and 11264 straddle only
// if sizes weren't multiples of 256 float4s -- they are: 2097152/786432/262144).
__global__ void cast_all(const float* __restrict__ x, const float* __restrict__ wq,
                         const float* __restrict__ wo, u16* __restrict__ xb,
                         u16* __restrict__ wqb, u16* __restrict__ wob) {
    const int i = blockIdx.x * blockDim.x + threadIdx.x;   // float4 index
    const float* in; u16* out; int j;
    if (i < 2097152)      { in = x;  out = xb;  j = i; }
    else if (i < 2883584) { in = wq; out = wqb; j = i - 2097152; }
    else                  { in = wo; out = wob; j = i - 2883584; }
    float4 f = ((const float4*)in)[j];
    u16x4v o;
    o.x = f2bf(f.x); o.y = f2bf(f.y); o.z = f2bf(f.z); o.w = f2bf(f.w);
    ((u16x4v*)out)[j] = o;
}

// ---------------- bt-GEMM: C[m,n] = sum_k A[m,k]*B[n,k] + bias[n] ----------------
// MODE 0: fp32 out, row-major ldc.
// MODE 1: qkv split epilogue -> qb (bf16, prescaled), kb (bf16), vT (bf16, [h][hd][8192]).
// T1: bijective XCD swizzle on flat block id (nwg%8==0 for both launches).
// R10 (kept): BK=64 halves barriers; (256,3) from R9; 8-chunk rotate staging.
// R8's dbuf was negative; m131-m141: this 2-phase structure is at its ceiling band.
template <int MODE>
__global__ __launch_bounds__(256, 3) void gemm_bt(
    const u16* __restrict__ A, const u16* __restrict__ B,
    const float* __restrict__ bias, float* __restrict__ Cf,
    u16* __restrict__ qb, u16* __restrict__ kb, u16* __restrict__ vT,
    int K, int ldc)
{
    __shared__ __align__(16) u16 As[128 * 64];
    __shared__ __align__(16) u16 Bs[128 * 64];
    const int tid = threadIdx.x;
    const int lane = tid & 63;
    const int w = tid >> 6;
    const int wm = (w >> 1) << 6;
    const int wn = (w & 1) << 6;
    const int r = lane & 15;
    const int q = lane >> 4;

    // XCD-aware bijective block swizzle (each XCD gets a contiguous panel chunk)
    const int nwgx = gridDim.x;
    const int flat = blockIdx.y * nwgx + blockIdx.x;
    const int cpx = (nwgx * gridDim.y) >> 3;
    const int swz = (flat & 7) * cpx + (flat >> 3);
    const int m0 = (swz / nwgx) << 7;
    const int n0 = (swz % nwgx) << 7;

    const f32x4 zero4 = {0.f, 0.f, 0.f, 0.f};
    f32x4 acc[4][4];
#pragma unroll
    for (int i = 0; i < 4; ++i)
#pragma unroll
        for (int j = 0; j < 4; ++j) acc[i][j] = zero4;

    const int nk = K >> 6;   // 64-wide K-steps
    for (int kt = 0; kt < nk; ++kt) {
        const int kk = kt << 6;
        // stage 128 rows x 64 cols per matrix: 8 chunks/row, rotate phys = (cg+row)&7
#pragma unroll
        for (int p = 0; p < 4; ++p) {
            const int idx = (p << 8) + tid;
            const int row = idx >> 3;
            const int cg = ((idx & 7) - row) & 7;
            gld_lds16(A + (m0 + row) * K + kk + (cg << 3), &As[idx << 3]);
            gld_lds16(B + (n0 + row) * K + kk + (cg << 3), &Bs[idx << 3]);
        }
        __syncthreads();
#pragma unroll
        for (int s = 0; s < 2; ++s) {
            bf16x8 af[4], bf[4];
#pragma unroll
            for (int i = 0; i < 4; ++i) {
                const int ra = wm + (i << 4) + r;
                af[i] = *(const bf16x8*)&As[(ra << 6) + ((((s << 2) + q + ra) & 7) << 3)];
                const int rb = wn + (i << 4) + r;
                bf[i] = *(const bf16x8*)&Bs[(rb << 6) + ((((s << 2) + q + rb) & 7) << 3)];
            }
#pragma unroll
            for (int i = 0; i < 4; ++i)
#pragma unroll
                for (int j = 0; j < 4; ++j)
                    acc[i][j] = __builtin_amdgcn_mfma_f32_16x16x32_bf16(af[i], bf[j], acc[i][j], 0, 0, 0);
        }
        __syncthreads();
    }

#pragma unroll
    for (int j = 0; j < 4; ++j) {
        const int col = n0 + wn + (j << 4) + r;
        const float bv = bias[col];
        if (MODE == 0) {
#pragma unroll
            for (int i = 0; i < 4; ++i)
#pragma unroll
                for (int ii = 0; ii < 4; ++ii) {
                    const int rowg = m0 + wm + (i << 4) + (q << 2) + ii;
                    Cf[rowg * ldc + col] = acc[i][j][ii] + bv;
                }
        } else {
            // wave-uniform region decode per j-group (16 cols never straddle 64/192 boundaries)
            const int c0 = n0 + wn + (j << 4);
            const int h = c0 / 192;
            const int rem = c0 - h * 192;
            const int region = rem >> 6;
            const int colp = (h << 6) + (rem - (region << 6)) + r;
            if (region == 0) {
#pragma unroll
                for (int i = 0; i < 4; ++i)
#pragma unroll
                    for (int ii = 0; ii < 4; ++ii) {
                        const int rowg = m0 + wm + (i << 4) + (q << 2) + ii;
                        qb[rowg * 1024 + colp] = f2bf((acc[i][j][ii] + bv) * QSCALE);
                    }
            } else if (region == 1) {
#pragma unroll
                for (int i = 0; i < 4; ++i)
#pragma unroll
                    for (int ii = 0; ii < 4; ++ii) {
                        const int rowg = m0 + wm + (i << 4) + (q << 2) + ii;
                        kb[rowg * 1024 + colp] = f2bf(acc[i][j][ii] + bv);
                    }
            } else {
                // V transposed: vT[colp][rowg], rowg contiguous -> packed 8B stores
#pragma unroll
                for (int i = 0; i < 4; ++i) {
                    const int rowg0 = m0 + wm + (i << 4) + (q << 2);
                    u16x4v vv;
                    vv.x = f2bf(acc[i][j][0] + bv);
                    vv.y = f2bf(acc[i][j][1] + bv);
                    vv.z = f2bf(acc[i][j][2] + bv);
                    vv.w = f2bf(acc[i][j][3] + bv);
                    *(u16x4v*)&vT[(size_t)colp * 8192 + rowg0] = vv;
                }
            }
        }
    }
}

// ---------------- flash attention, S^T formulation, 64 q-rows per wave ----------------
// EXACT R11 kernel (session-best total 249.4 us). History of the ~24% no-pipe-busy
// stall: MFMA cuts (R1,R6) neutral; LDS-read/barrier cuts (R4) neutral; in-wave
// pipeline (R7) REGRESSED; wave-stagger (R11) counter-neutral; direct-from-cache K/V
// (R12) REGRESSED 82->136 us (per-lane 1KB/8KB-stride frag reads = 1 cache line per
// lane, 64 lines/instr -- LDS staging IS the coalescing enabler; do not de-stage).
// Only VALU-instruction cuts ever moved time (R5: -12%). Remaining gap requires the
// full co-designed 8-phase port (m152 race risk) -- not attempted blind.
// __launch_bounds__(256,2). DO NOT use (256,4): spills (prior session).
__global__ __launch_bounds__(256, 2) void attn(
    const u16* __restrict__ qb, const u16* __restrict__ kb,
    const u16* __restrict__ vT, u16* __restrict__ vals)
{
    // S as Q staging at init (256 rows x 64), then two 16KB KV buffers:
    // buf A = S[8192:16384) (even kt), buf B = S[0:8192) (odd kt).
    // K part: [row 64][64], 16B chunks, phys chunk = (log + row) & 7
    // V part (at +4096): [hd 64][kv 64], 16B chunks, phys chunk = (log + hd) & 7
    __shared__ __align__(16) u16 S[16384];

    const int tid  = threadIdx.x;
    const int lane = tid & 63;
    const int w    = tid >> 6;
    const int c    = lane & 31;   // row index of 32x32 A-frags / col of C-frags
    const int h2   = lane >> 5;   // lane half
    const int head = blockIdx.x;
    const int q0   = blockIdx.y << 8;   // 256 q-rows per block
    const int b    = blockIdx.z;
    const size_t rowbase = (size_t)b * 2048;

    // ---- stage Q (256 rows x 8 chunks of 8 u16), rotate swizzle ----
#pragma unroll
    for (int p = 0; p < 8; ++p) {
        const int idx = (p << 8) + tid;
        const int row = idx >> 3;
        const int cg  = ((idx & 7) - row) & 7;
        gld_lds16(qb + (rowbase + q0 + row) * 1024 + (head << 6) + (cg << 3), &S[idx << 3]);
    }
    __syncthreads();

    // ---- Q B-frags (loop-invariant): bq[dc][nt], lane holds Q[qr][16dc+8*h2+j] ----
    bf16x8 bq[4][2];
#pragma unroll
    for (int nt = 0; nt < 2; ++nt) {
        const int qr = (w << 6) + (nt << 5) + c;
#pragma unroll
        for (int dc = 0; dc < 4; ++dc)
            bq[dc][nt] = *(const bf16x8*)&S[(qr << 6) + ((((dc << 1) + h2 + qr) & 7) << 3)];
    }
    __syncthreads();  // all waves done reading Q before KV staging overwrites S

    // ---- K/V staging geometry (per-thread, kt-invariant) ----
    const int srow8 = tid >> 3;                      // 0..31 (pass 1 at +32 rows)
    const int scg   = ((tid & 7) - srow8) & 7;       // rotate phase ((row+32)&7 == row&7)
    const u16* gK = kb + (rowbase + srow8) * 1024 + (head << 6) + (scg << 3);
    const u16* gV = vT + (size_t)((head << 6) + srow8) * 8192 + rowbase + (scg << 3);

    // stage kt=0 into buffer A
    {
        u16* buf = S + 8192;
        gld_lds16(gK,             &buf[tid << 3]);
        gld_lds16(gK + 32 * 1024, &buf[2048 + (tid << 3)]);
        gld_lds16(gV,             &buf[4096 + (tid << 3)]);
        gld_lds16(gV + 32 * 8192, &buf[6144 + (tid << 3)]);
    }
    __syncthreads();

    // per-lane loop-invariant fragment addresses (u16 idx), rotate swizzle.
    // K log chunk = 2dc+h2; V log chunk = 2*((mt<<1)|c16)+h2 -> SAME table aF[4].
    int aF[4];
#pragma unroll
    for (int i = 0; i < 4; ++i)
        aF[i] = (c << 6) + ((((i << 1) + h2 + c) & 7) << 3);

    // wave-staggered mt order: mm is the compile-time pass index, the actual mt
    // processed is mt = mtw ^ mm. Pre-select addresses so all array indexing in the
    // hot loop is compile-time ([mm][.]).
    const int mtw = w & 1;
    int aK[2][4];   // K frag addr for pass mm, dc
    int aV[2][4];   // V frag addr for pass mm, (ht<<1)|c16
#pragma unroll
    for (int i = 0; i < 4; ++i) {
        const int a0 = aF[i];            // mt=0 (row offset 0)
        const int a1 = aF[i] + 2048;     // mt=1 (+32 rows = +2048 u16)
        aK[0][i] = mtw ? a1 : a0;
        aK[1][i] = mtw ? a0 : a1;
    }
#pragma unroll
    for (int ht = 0; ht < 2; ++ht)
#pragma unroll
        for (int c16 = 0; c16 < 2; ++c16) {
            const int i = (ht << 1) | c16;
            const int v0 = aF[c16] + (ht << 11);       // mt=0
            const int v1 = aF[2 + c16] + (ht << 11);   // mt=1
            aV[0][i] = mtw ? v1 : v0;
            aV[1][i] = mtw ? v0 : v1;
        }

    f32x16 oacc[2][2];            // oacc[ht][nt]
    f32x2 la2[2];                 // l partial sums (lane-local column sums)
    f32x16 zero16;
#pragma unroll
    for (int i = 0; i < 16; ++i) {
        zero16[i] = 0.f;
        oacc[0][0][i] = 0.f; oacc[0][1][i] = 0.f;
        oacc[1][0][i] = 0.f; oacc[1][1][i] = 0.f;
    }
    la2[0][0] = 0.f; la2[0][1] = 0.f;
    la2[1][0] = 0.f; la2[1][1] = 0.f;

    const u16* gKr = gK + 65536;   // +64 rows * 1024 per kt
    const u16* gVr = gV + 64;      // +64 kv per kt

    for (int kt = 0; kt < 32; ++kt) {
        const int cur = kt & 1;
        if (kt > 0) __syncthreads();   // drains prefetch (issued a full kt ago) + orders buffers
        u16* bufP = (cur == 0) ? (S + 0) : (S + 8192);       // prefetch target (kt+1)
        const u16* bufC = (cur == 0) ? (S + 8192) : (S + 0); // compute source (kt)
        if (kt < 31) {
            gld_lds16(gKr,             &bufP[tid << 3]);
            gld_lds16(gKr + 32 * 1024, &bufP[2048 + (tid << 3)]);
            gld_lds16(gVr,             &bufP[4096 + (tid << 3)]);
            gld_lds16(gVr + 32 * 8192, &bufP[6144 + (tid << 3)]);
            gKr += 65536;
            gVr += 64;
        }
        const u16* Ks  = bufC;
        const u16* VTs = bufC + 4096;

#pragma unroll
        for (int mm = 0; mm < 2; ++mm) {
            // ---- S^T = K Q^T for this wave's mm-th kv-32 tile ----
            // dc=0 peeled with zero16 C-operand: no per-mt accumulator re-zero movs.
            __builtin_amdgcn_s_setprio(1);
            const bf16x8 ak0 = *(const bf16x8*)&Ks[aK[mm][0]];
            f32x16 s0 = __builtin_amdgcn_mfma_f32_32x32x16_bf16(ak0, bq[0][0], zero16, 0, 0, 0);
            f32x16 s1 = __builtin_amdgcn_mfma_f32_32x32x16_bf16(ak0, bq[0][1], zero16, 0, 0, 0);
#pragma unroll
            for (int dc = 1; dc < 4; ++dc) {
                const bf16x8 ak = *(const bf16x8*)&Ks[aK[mm][dc]];
                s0 = __builtin_amdgcn_mfma_f32_32x32x16_bf16(ak, bq[dc][0], s0, 0, 0, 0);
                s1 = __builtin_amdgcn_mfma_f32_32x32x16_bf16(ak, bq[dc][1], s1, 0, 0, 0);
            }
            __builtin_amdgcn_s_setprio(0);

            // V^T A-frags for this kv-32 tile, shared across both nt
            bf16x8 av[4];   // [ht*2 + c16]
#pragma unroll
            for (int i = 0; i < 4; ++i)
                av[i] = *(const bf16x8*)&VTs[aV[mm][i]];

#pragma unroll
            for (int nt = 0; nt < 2; ++nt) {
                const f32x16& sv = (nt == 0) ? s0 : s1;   // compile-time select
                bf16x8 A0v, A1v;
                smpack(sv, la2[nt], A0v, A1v);

                __builtin_amdgcn_s_setprio(1);
                // O^T += V^T P^T
#pragma unroll
                for (int ht = 0; ht < 2; ++ht) {
                    oacc[ht][nt] = __builtin_amdgcn_mfma_f32_32x32x16_bf16(av[(ht << 1) | 0], A0v, oacc[ht][nt], 0, 0, 0);
                    oacc[ht][nt] = __builtin_amdgcn_mfma_f32_32x32x16_bf16(av[(ht << 1) | 1], A1v, oacc[ht][nt], 0, 0, 0);
                }
                __builtin_amdgcn_s_setprio(0);
            }
        }
    }

    // ---- epilogue: l = own-half partial + other-half partial (shfl_xor 32) ----
#pragma unroll
    for (int nt = 0; nt < 2; ++nt) {
        float myl = la2[nt][0] + la2[nt][1];
        myl += __shfl_xor(myl, 32, 64);
        const float inv = 1.f / myl;
        const size_t orow = rowbase + q0 + (w << 6) + (nt << 5) + c;
#pragma unroll
        for (int ht = 0; ht < 2; ++ht)
#pragma unroll
            for (int r4 = 0; r4 < 4; ++r4) {
                u16x4v vv;
                vv.x = f2bf(oacc[ht][nt][4 * r4 + 0] * inv);
                vv.y = f2bf(oacc[ht][nt][4 * r4 + 1] * inv);
                vv.z = f2bf(oacc[ht][nt][4 * r4 + 2] * inv);
                vv.w = f2bf(oacc[ht][nt][4 * r4 + 3] * inv);
                const int hd0 = (ht << 5) + (r4 << 3) + (h2 << 2);
                *(u16x4v*)&vals[orow * 1024 + (head << 6) + hd0] = vv;
            }
    }
}

// ---------------- launcher ----------------
extern "C" void kernel_launch(void* const* d_in, const int* in_sizes, int n_in,
                              void* d_out, int out_size, void* d_ws, size_t ws_size,
                              hipStream_t stream) {
    (void)in_sizes; (void)n_in; (void)out_size; (void)ws_size;
    const float* x     = (const float*)d_in[0];   // [4,2048,1024]
    const float* w_qkv = (const float*)d_in[1];   // [3072,1024]
    const float* b_qkv = (const float*)d_in[2];   // [3072]
    const float* w_o   = (const float*)d_in[3];   // [1024,1024]
    const float* b_o   = (const float*)d_in[4];   // [1024]
    float* out = (float*)d_out;                   // [4,2048,1024]

    char* ws = (char*)d_ws;
    u16* xb    = (u16*)(ws);                          // 16 MB  [8192,1024]
    u16* wqkvb = (u16*)(ws + (size_t)(16 << 20));     //  6 MB  [3072,1024]
    u16* wob   = (u16*)(ws + (size_t)(22 << 20));     //  2 MB  [1024,1024]
    u16* qb    = (u16*)(ws + (size_t)(24 << 20));     // 16 MB  [8192,1024]
    u16* kb    = (u16*)(ws + (size_t)(40 << 20));     // 16 MB  [8192,1024]
    u16* vTb   = (u16*)(ws + (size_t)(56 << 20));     // 16 MB  [16,64,8192]
    u16* valsb = (u16*)(ws + (size_t)(72 << 20));     // 16 MB  [8192,1024]

    // fused cast: x (2097152 f4) + w_qkv (786432 f4) + w_o (262144 f4) = 3145728 f4
    cast_all<<<12288, 256, 0, stream>>>(x, w_qkv, w_o, xb, wqkvb, wob);

    // qkv = x @ w_qkv^T + b_qkv -> split qb (prescaled) / kb / vT
    gemm_bt<1><<<dim3(24, 64), 256, 0, stream>>>(xb, wqkvb, b_qkv, nullptr,
                                                 qb, kb, vTb, 1024, 3072);

    // attention -> vals (bf16); 512 blocks = exactly 2/CU, (b,h) XCD-local
    attn<<<dim3(16, 8, 4), 256, 0, stream>>>(qb, kb, vTb, valsb);

    // out = vals @ w_o^T + b_o  (fp32 out)
    gemm_bt<0><<<dim3(8, 64), 256, 0, stream>>>(valsb, wob, b_o, out,
                                                nullptr, nullptr, nullptr, 1024, 1024);
}